// Round 4
// baseline (297.210 us; speedup 1.0000x reference)
//
#include <hip/hip_runtime.h>
#include <cstdint>
#include <cstddef>

// B=16, N=1024, D=768, H=12, HS=64, L=2
// R10 changes vs R9:
//  - dense GEMMs: revert to R6 gemm_core (128x128, BK=32, 4 waves) but with
//    4 LDS buffers / depth-3 prefetch (issue tile it+3 during it) and 64KB
//    LDS + __launch_bounds__(256,2) -> 2 blocks/CU. Theory: R7-R9's 256²
//    1-block/CU schedules exposed full load latency at every lockstep wait;
//    TLP across 2 independent blocks + deeper prefetch hides it (m97's real
//    mechanism: 2-3 blocks/CU).
//  - circ: revert to R6 128² circ verbatim (41.2µs measured, depth-3,
//    3 blocks/CU) — R8/R9 256² circ was 43.6-46.0.
//  - pack_all merged kernel kept. No dynamic LDS, no hipFuncSetAttribute.
//
// ws layout (bytes): unchanged.
//  [0, 25165824)          slotA : xn_bf16 -> z1_bf16
//  [25165824, 50331648)   Vt    : gemm1 out ; reused as gbf after circ
//  [50331648, 75497472)   slotX : x2_bf16 (circ out, read by gemmf1 + final)
//  [75497472, 76677120)   W2t
//  [76677120, 79036416)   Wft

typedef __attribute__((ext_vector_type(8))) short bf16x8;
typedef __attribute__((ext_vector_type(4))) float f32x4;
typedef __attribute__((ext_vector_type(4))) unsigned short us4;

__device__ __forceinline__ unsigned short f2bf(float f) {
  unsigned int u = __builtin_bit_cast(unsigned int, f);
  u += 0x7FFFu + ((u >> 16) & 1u);
  return (unsigned short)(u >> 16);
}
__device__ __forceinline__ float bf2f(unsigned short u) {
  return __builtin_bit_cast(float, (unsigned int)u << 16);
}

__device__ __forceinline__ void g2l16(const void* g, void* l) {
  __builtin_amdgcn_global_load_lds(
      (const __attribute__((address_space(1))) unsigned int*)g,
      (__attribute__((address_space(3))) unsigned int*)l,
      16, 0, 0);
}

// raw barrier: wait for all but n outstanding vmem, all lds ops, then barrier.
#define WAITB(n) asm volatile("s_waitcnt vmcnt(" #n ") lgkmcnt(0)\n\ts_barrier" ::: "memory")

// ---------------- pack kernel (merged) ----------------
__global__ __launch_bounds__(256) void pack_all(const float* __restrict__ Wv,
                                                const float* __restrict__ Wf,
                                                unsigned short* __restrict__ W2t,
                                                unsigned short* __restrict__ Wft) {
  int bid = blockIdx.x;
  if (bid < 2304) {
    int o = bid * 256 + threadIdx.x;
    int np = o / 768, d = o - np * 768;
    int h = np >> 6, k = np & 63;
    W2t[o] = f2bf(Wv[h * 49152 + d * 64 + k]);
  } else {
    int o = (bid - 2304) * 256 + threadIdx.x;
    int l = o / 589824, rem = o - l * 589824;
    int np = rem / 768, d = rem - np * 768;
    Wft[o] = f2bf(Wf[l * 589824 + d * 768 + np]);
  }
}

// ---------------- row kernels ----------------
__device__ __forceinline__ void wave_reduce2(float& s, float& s2) {
#pragma unroll
  for (int off = 32; off > 0; off >>= 1) {
    s += __shfl_down(s, off);
    s2 += __shfl_down(s2, off);
  }
  s = __shfl(s, 0);
  s2 = __shfl(s2, 0);
}

__global__ __launch_bounds__(256) void ln1_kernel(const float* __restrict__ x,
                                                  const float* __restrict__ sc,
                                                  const float* __restrict__ bi,
                                                  unsigned short* __restrict__ out) {
  int row = blockIdx.x * 4 + (threadIdx.x >> 6);
  int lane = threadIdx.x & 63;
  size_t base = (size_t)row * 768;
  float4 v[3];
#pragma unroll
  for (int j = 0; j < 3; ++j) v[j] = *(const float4*)(x + base + lane * 4 + j * 256);
  float s = 0.f, s2 = 0.f;
#pragma unroll
  for (int j = 0; j < 3; ++j) {
    s += v[j].x + v[j].y + v[j].z + v[j].w;
    s2 += v[j].x * v[j].x + v[j].y * v[j].y + v[j].z * v[j].z + v[j].w * v[j].w;
  }
  wave_reduce2(s, s2);
  float mu = s * (1.0f / 768.0f);
  float var = s2 * (1.0f / 768.0f) - mu * mu;
  float r = rsqrtf(var + 1e-6f);
#pragma unroll
  for (int j = 0; j < 3; ++j) {
    int d = lane * 4 + j * 256;
    float4 scv = *(const float4*)(sc + d);
    float4 biv = *(const float4*)(bi + d);
    us4 o;
    o[0] = f2bf((v[j].x - mu) * r * scv.x + biv.x);
    o[1] = f2bf((v[j].y - mu) * r * scv.y + biv.y);
    o[2] = f2bf((v[j].z - mu) * r * scv.z + biv.z);
    o[3] = f2bf((v[j].w - mu) * r * scv.w + biv.w);
    *(us4*)(out + base + d) = o;
  }
}

__global__ __launch_bounds__(256) void lnswish_kernel(const unsigned short* __restrict__ g,
                                                      const float* __restrict__ sc,
                                                      const float* __restrict__ bi,
                                                      unsigned short* __restrict__ out) {
  int row = blockIdx.x * 4 + (threadIdx.x >> 6);
  int lane = threadIdx.x & 63;
  size_t base = (size_t)row * 768;
  float v[3][4];
#pragma unroll
  for (int j = 0; j < 3; ++j) {
    us4 gv = *(const us4*)(g + base + lane * 4 + j * 256);
#pragma unroll
    for (int q = 0; q < 4; ++q) v[j][q] = bf2f(gv[q]);
  }
  float s = 0.f, s2 = 0.f;
#pragma unroll
  for (int j = 0; j < 3; ++j)
#pragma unroll
    for (int q = 0; q < 4; ++q) { s += v[j][q]; s2 += v[j][q] * v[j][q]; }
  wave_reduce2(s, s2);
  float mu = s * (1.0f / 768.0f);
  float var = s2 * (1.0f / 768.0f) - mu * mu;
  float r = rsqrtf(var + 1e-6f);
#pragma unroll
  for (int j = 0; j < 3; ++j) {
    int d = lane * 4 + j * 256;
    float4 scv = *(const float4*)(sc + d);
    float4 biv = *(const float4*)(bi + d);
    const float* scp = &scv.x;
    const float* bip = &biv.x;
    us4 o;
#pragma unroll
    for (int q = 0; q < 4; ++q) {
      float z = (v[j][q] - mu) * r * scp[q] + bip[q];
      o[q] = f2bf(z / (1.0f + __expf(-z)));
    }
    *(us4*)(out + base + d) = o;
  }
}

__global__ __launch_bounds__(256) void final_kernel(const unsigned short* __restrict__ g,
                                                    const float* __restrict__ sc,
                                                    const float* __restrict__ bi,
                                                    const unsigned short* __restrict__ x2,
                                                    float* __restrict__ out) {
  int row = blockIdx.x * 4 + (threadIdx.x >> 6);
  int lane = threadIdx.x & 63;
  size_t base = (size_t)row * 768;
  float v[3][4];
#pragma unroll
  for (int j = 0; j < 3; ++j) {
    us4 gv = *(const us4*)(g + base + lane * 4 + j * 256);
#pragma unroll
    for (int q = 0; q < 4; ++q) v[j][q] = bf2f(gv[q]);
  }
  float s = 0.f, s2 = 0.f;
#pragma unroll
  for (int j = 0; j < 3; ++j)
#pragma unroll
    for (int q = 0; q < 4; ++q) { s += v[j][q]; s2 += v[j][q] * v[j][q]; }
  wave_reduce2(s, s2);
  float mu = s * (1.0f / 768.0f);
  float var = s2 * (1.0f / 768.0f) - mu * mu;
  float r = rsqrtf(var + 1e-6f);
#pragma unroll
  for (int j = 0; j < 3; ++j) {
    int d = lane * 4 + j * 256;
    float4 scv = *(const float4*)(sc + d);
    float4 biv = *(const float4*)(bi + d);
    us4 xv = *(const us4*)(x2 + base + d);
    const float* scp = &scv.x;
    const float* bip = &biv.x;
    float4 o;
    float* op = &o.x;
#pragma unroll
    for (int q = 0; q < 4; ++q) {
      float z = (v[j][q] - mu) * r * scp[q] + bip[q];
      float sw = z / (1.0f + __expf(-z));
      float t = sw + bf2f(xv[q]);
      float ax = fabsf(t);
      op[q] = ax + __logf(1.0f + __expf(-2.0f * ax)) - 0.69314718055994531f;
    }
    *(float4*)(out + base + d) = o;
  }
}

// ---------- async GEMM core: 128x128, BK=32, 4-buffer depth-3 pipeline ----
// Per iter: WAITB(8) lands stage(it) (it+1, it+2 stay in flight), issue
// stage(it+3), compute(it). Buffer (it+3)&3 was last read at GCOMP(it-1),
// whose ds_reads completed before this iter's WAITB barrier (lgkmcnt(0)).
__device__ __forceinline__ void gemm_core(const unsigned short* __restrict__ A,
                                          const unsigned short* __restrict__ Bt,
                                          int K, int m0, int n0,
                                          unsigned short* sA, unsigned short* sB,
                                          f32x4 acc[4][4]) {
  const int tid = threadIdx.x;
  const int wave = tid >> 6, lane = tid & 63;
  const int wm = (wave >> 1) << 6, wn = (wave & 1) << 6;
  const int fm = lane & 15, fq = lane >> 4;
  const int r0 = tid >> 2, r1 = r0 + 64;
  const int cg = tid & 3;
  const int cs0 = (cg ^ ((r0 >> 1) & 3)) << 3;
  const int cs1 = (cg ^ ((r1 >> 1) & 3)) << 3;
  const int ld0 = r0 * 32 + (cg << 3);
  const int ld1 = r1 * 32 + (cg << 3);
  const int niter = K >> 5;

#define STAGE(k0v, buf)                                                       \
  {                                                                           \
    unsigned short* dA = sA + (buf) * 4096;                                   \
    unsigned short* dB = sB + (buf) * 4096;                                   \
    g2l16(A + (size_t)(m0 + r0) * K + (k0v) + cs0, dA + ld0);                 \
    g2l16(Bt + (size_t)(n0 + r0) * K + (k0v) + cs0, dB + ld0);                \
    g2l16(A + (size_t)(m0 + r1) * K + (k0v) + cs1, dA + ld1);                 \
    g2l16(Bt + (size_t)(n0 + r1) * K + (k0v) + cs1, dB + ld1);                \
  }
#define GCOMP(bc)                                                             \
  {                                                                           \
    const unsigned short* pA = sA + (bc) * 4096;                              \
    const unsigned short* pB = sB + (bc) * 4096;                              \
    bf16x8 aq[4], bq[4];                                                      \
    _Pragma("unroll") for (int t = 0; t < 4; ++t) {                           \
      int ra = wm + (t << 4) + fm;                                            \
      int rb = wn + (t << 4) + fm;                                            \
      aq[t] = *(const bf16x8*)(pA + (ra << 5) + ((fq ^ ((ra >> 1) & 3)) << 3)); \
      bq[t] = *(const bf16x8*)(pB + (rb << 5) + ((fq ^ ((rb >> 1) & 3)) << 3)); \
    }                                                                         \
    _Pragma("unroll") for (int mt = 0; mt < 4; ++mt)                          \
    _Pragma("unroll") for (int nt = 0; nt < 4; ++nt)                          \
      acc[mt][nt] = __builtin_amdgcn_mfma_f32_16x16x32_bf16(aq[mt], bq[nt],   \
                                                            acc[mt][nt], 0, 0, 0); \
  }

  STAGE(0, 0);
  STAGE(32, 1);
  STAGE(64, 2);
  for (int it = 0; it < niter - 2; ++it) {
    WAITB(8);                    // stage(it) landed; it+1, it+2 in flight
    if (it + 3 < niter) STAGE((it + 3) << 5, (it + 3) & 3);
    GCOMP(it & 3);
  }
  WAITB(4);
  GCOMP((niter - 2) & 3);
  WAITB(0);
  GCOMP((niter - 1) & 3);
#undef STAGE
#undef GCOMP
}

__device__ __forceinline__ void decode_mn_768(int f, int& m0, int& n0) {
  int xcd = f & 7, s = f >> 3;
  int g = s / 6, bx = s - g * 6;
  m0 = (xcd + g * 8) << 7;
  n0 = bx << 7;
}

// GEMM1: xn @ W2t -> Vt[h][b*64+k][n] (bf16)
__global__ __launch_bounds__(256, 2) void gemm1_kernel(const unsigned short* __restrict__ A,
                                                       const unsigned short* __restrict__ Bt,
                                                       unsigned short* __restrict__ Vt) {
  __shared__ unsigned short sA[4 * 4096];
  __shared__ unsigned short sB[4 * 4096];
  f32x4 acc[4][4] = {};
  int m0, n0;
  decode_mn_768(blockIdx.x, m0, n0);
  gemm_core(A, Bt, 768, m0, n0, sA, sB, acc);
  const int wave = threadIdx.x >> 6, lane = threadIdx.x & 63;
  const int wm = (wave >> 1) << 6, wn = (wave & 1) << 6;
  const int fm = lane & 15, fq = lane >> 4;
#pragma unroll
  for (int mt = 0; mt < 4; ++mt) {
    int rowb = m0 + wm + (mt << 4) + (fq << 2);
    int b = rowb >> 10, n = rowb & 1023;
#pragma unroll
    for (int nt = 0; nt < 4; ++nt) {
      int col = n0 + wn + (nt << 4) + fm;
      int h = col >> 6, ck = col & 63;
      size_t off = ((size_t)h << 20) + (size_t)((b << 6) + ck) * 1024 + n;
      us4 v;
#pragma unroll
      for (int r = 0; r < 4; ++r) v[r] = f2bf(acc[mt][nt][r]);
      *(us4*)(Vt + off) = v;
    }
  }
}

// FFN GEMM: A(bf16) @ Wt + bias -> g (bf16)
__global__ __launch_bounds__(256, 2) void gemmf_kernel(const unsigned short* __restrict__ A,
                                                       const unsigned short* __restrict__ Bt,
                                                       const float* __restrict__ bias,
                                                       unsigned short* __restrict__ g) {
  __shared__ unsigned short sA[4 * 4096];
  __shared__ unsigned short sB[4 * 4096];
  f32x4 acc[4][4] = {};
  int m0, n0;
  decode_mn_768(blockIdx.x, m0, n0);
  gemm_core(A, Bt, 768, m0, n0, sA, sB, acc);
  const int wave = threadIdx.x >> 6, lane = threadIdx.x & 63;
  const int wm = (wave >> 1) << 6, wn = (wave & 1) << 6;
  const int fm = lane & 15, fq = lane >> 4;
#pragma unroll
  for (int mt = 0; mt < 4; ++mt) {
    int rowb = m0 + wm + (mt << 4) + (fq << 2);
#pragma unroll
    for (int nt = 0; nt < 4; ++nt) {
      int col = n0 + wn + (nt << 4) + fm;
      float bc = bias[col];
#pragma unroll
      for (int r = 0; r < 4; ++r)
        g[(size_t)(rowb + r) * 768 + col] = f2bf(acc[mt][nt][r] + bc);
    }
  }
}

// circGEMM (R6 verbatim): A from alpha (circulant, LDS shifted copies),
// B = Vt_h, 4-deep B pipeline, depth-3. epilogue: x2 = x + y (bf16).
__global__ __launch_bounds__(256, 3) void circ_kernel(const float* __restrict__ alpha,
                                                      const unsigned short* __restrict__ Vt,
                                                      const float* __restrict__ xin,
                                                      unsigned short* __restrict__ x2bf) {
  __shared__ unsigned short sAc[8 * 1168];   // 8 shift-copies of alpha window
  __shared__ unsigned short sB[4 * 4096];    // 4-deep B pipeline
  f32x4 acc[4][4] = {};
  int f = blockIdx.x;
  int xcd = f & 7, s = f >> 3;
  int h = s >> 3, t = s & 7;
  int mr = xcd >> 1, nr = xcd & 1;
  int m0 = ((mr << 1) + (t >> 2)) << 7;
  int n0 = ((nr << 2) + (t & 3)) << 7;

  const int tid = threadIdx.x;
  const int wave = tid >> 6, lane = tid & 63;
  const int wm = (wave >> 1) << 6, wn = (wave & 1) << 6;
  const int fm = lane & 15, fq = lane >> 4;

  const float* ah = alpha + (h << 10);
#pragma unroll
  for (int c = 0; c < 8; ++c)
    for (int u = tid; u < 1160; u += 256)
      sAc[c * 1168 + u] = f2bf(ah[(m0 - 897 - u - c) & 1023]);
  asm volatile("s_waitcnt vmcnt(0)" ::: "memory");  // flush fill loads from vmcnt

  const unsigned short* Bt = Vt + ((size_t)h << 20);
  const int r0 = tid >> 2, r1 = r0 + 64;
  const int cg = tid & 3;
  const int cs0 = (cg ^ ((r0 >> 1) & 3)) << 3;
  const int cs1 = (cg ^ ((r1 >> 1) & 3)) << 3;
  const int ld0 = r0 * 32 + (cg << 3);
  const int ld1 = r1 * 32 + (cg << 3);

#define STAGEB(k0v, buf)                                                      \
  {                                                                           \
    unsigned short* dB = sB + (buf) * 4096;                                   \
    g2l16(Bt + (size_t)(n0 + r0) * 1024 + (k0v) + cs0, dB + ld0);             \
    g2l16(Bt + (size_t)(n0 + r1) * 1024 + (k0v) + cs1, dB + ld1);             \
  }
#define CCOMP(it)                                                             \
  {                                                                           \
    const unsigned short* pB = sB + ((it) & 3) * 4096;                        \
    int k0v = (it) << 5;                                                      \
    bf16x8 aq[4], bq[4];                                                      \
    _Pragma("unroll") for (int t_ = 0; t_ < 4; ++t_) {                        \
      int rl = wm + (t_ << 4) + fm;                                           \
      int d = k0v + (fq << 3) + 127 - rl;                                     \
      int c = d & 7;                                                          \
      aq[t_] = *(const bf16x8*)(sAc + c * 1168 + (d - c));                    \
      int rb = wn + (t_ << 4) + fm;                                           \
      bq[t_] = *(const bf16x8*)(pB + (rb << 5) + ((fq ^ ((rb >> 1) & 3)) << 3)); \
    }                                                                         \
    _Pragma("unroll") for (int mt = 0; mt < 4; ++mt)                          \
    _Pragma("unroll") for (int nt = 0; nt < 4; ++nt)                          \
      acc[mt][nt] = __builtin_amdgcn_mfma_f32_16x16x32_bf16(aq[mt], bq[nt],   \
                                                            acc[mt][nt], 0, 0, 0); \
  }

  STAGEB(0, 0);
  STAGEB(32, 1);
  STAGEB(64, 2);
  for (int it = 0; it < 30; ++it) {
    WAITB(4);                     // stage(it) landed; it+1, it+2 in flight
    if (it < 29) STAGEB((it + 3) << 5, (it + 3) & 3);
    CCOMP(it);
  }
  WAITB(2);
  CCOMP(30);
  WAITB(0);
  CCOMP(31);
#undef STAGEB

  // epilogue: x2 = x + y (bf16)
#pragma unroll
  for (int mt = 0; mt < 4; ++mt) {
    int ib = m0 + wm + (mt << 4) + (fq << 2);
#pragma unroll
    for (int nt = 0; nt < 4; ++nt) {
      int c = n0 + wn + (nt << 4) + fm;
      int b = c >> 6, k = c & 63;
      size_t off = ((size_t)(b << 10) + ib) * 768 + (h << 6) + k;
#pragma unroll
      for (int r = 0; r < 4; ++r) {
        float val = acc[mt][nt][r] + xin[off + (size_t)r * 768];
        x2bf[off + (size_t)r * 768] = f2bf(val);
      }
    }
  }
}

extern "C" void kernel_launch(void* const* d_in, const int* in_sizes, int n_in,
                              void* d_out, int out_size, void* d_ws, size_t ws_size,
                              hipStream_t stream) {
  const float* x = (const float*)d_in[0];
  const float* ln1_s = (const float*)d_in[1];
  const float* ln1_b = (const float*)d_in[2];
  const float* Wv = (const float*)d_in[3];
  const float* alpha = (const float*)d_in[4];
  const float* Wf = (const float*)d_in[5];
  const float* bf = (const float*)d_in[6];
  const float* lnf_s = (const float*)d_in[7];
  const float* lnf_b = (const float*)d_in[8];
  float* out = (float*)d_out;

  char* ws = (char*)d_ws;
  unsigned short* slotA = (unsigned short*)ws;                   // xn -> z1
  unsigned short* Vt = (unsigned short*)(ws + 25165824);         // Vt -> gbf
  unsigned short* gbf = Vt;
  unsigned short* slotX = (unsigned short*)(ws + 50331648);      // x2 bf16
  unsigned short* W2t = (unsigned short*)(ws + 75497472);
  unsigned short* Wft = (unsigned short*)(ws + 76677120);

  pack_all<<<6912, 256, 0, stream>>>(Wv, Wf, W2t, Wft);

  ln1_kernel<<<4096, 256, 0, stream>>>(x, ln1_s, ln1_b, slotA);
  gemm1_kernel<<<768, 256, 0, stream>>>(slotA, W2t, Vt);
  circ_kernel<<<768, 256, 0, stream>>>(alpha, Vt, x, slotX);
  gemmf_kernel<<<768, 256, 0, stream>>>(slotX, Wft, bf, gbf);
  lnswish_kernel<<<4096, 256, 0, stream>>>(gbf, lnf_s, lnf_b, slotA);
  gemmf_kernel<<<768, 256, 0, stream>>>(slotA, Wft + 589824, bf + 768, gbf);
  final_kernel<<<4096, 256, 0, stream>>>(gbf, lnf_s + 768, lnf_b + 768, slotX, out);
}

// Round 7
// 277.880 us; speedup vs baseline: 1.0696x; 1.0696x over previous
//
#include <hip/hip_runtime.h>
#include <cstdint>
#include <cstddef>

// B=16, N=1024, D=768, H=12, HS=64, L=2
// R13: bisect after R11/R12 died at container level (4 attempts).
//  - Base = R8 verbatim (best measured 270.3): pack_all, ln1, gemm1_256,
//    circ256_kernel, gemmf_256 (FFN layer 0), lnswish_kernel.
//  - ONE fused kernel swapped in: gemmf_ln1 (NON-template, uniform staging,
//    no predicated global_load_lds) replaces layer-1 gemmf_256+final_kernel.
//    64x768 full-row tile, 8 waves x 96 cols, BK=32 2-buffer, grid 256,
//    104KB dynamic LDS. Epilogue: bias -> block-local LN -> swish ->
//    +x2 residual -> log_cosh -> f32 out.
//  - Hardening vs R11/R12: no template kernel addresses in
//    hipFuncSetAttribute; all 512 threads issue identical load counts
//    (waves 4-7 duplicate the A-tile loads -- same addresses, same data).
//
// ws layout (bytes): unchanged.
//  [0, 25165824)          slotA : xn_bf16 -> z1_bf16
//  [25165824, 50331648)   Vt    : gemm1 out ; reused as gbf
//  [50331648, 75497472)   slotX : x2_bf16 (circ out)
//  [75497472, 76677120)   W2t
//  [76677120, 79036416)   Wft

typedef __attribute__((ext_vector_type(8))) short bf16x8;
typedef __attribute__((ext_vector_type(4))) float f32x4;
typedef __attribute__((ext_vector_type(4))) unsigned short us4;

__device__ __forceinline__ unsigned short f2bf(float f) {
  unsigned int u = __builtin_bit_cast(unsigned int, f);
  u += 0x7FFFu + ((u >> 16) & 1u);
  return (unsigned short)(u >> 16);
}
__device__ __forceinline__ float bf2f(unsigned short u) {
  return __builtin_bit_cast(float, (unsigned int)u << 16);
}

__device__ __forceinline__ void g2l16(const void* g, void* l) {
  __builtin_amdgcn_global_load_lds(
      (const __attribute__((address_space(1))) unsigned int*)g,
      (__attribute__((address_space(3))) unsigned int*)l,
      16, 0, 0);
}

#define WAITB(n) asm volatile("s_waitcnt vmcnt(" #n ") lgkmcnt(0)\n\ts_barrier" ::: "memory")
#define BARX asm volatile("s_waitcnt lgkmcnt(0)\n\ts_barrier" ::: "memory")
#define BARV(n) asm volatile("s_waitcnt vmcnt(" #n ") lgkmcnt(0)\n\ts_barrier" ::: "memory")

// ---------------- pack kernel (merged) ----------------
__global__ __launch_bounds__(256) void pack_all(const float* __restrict__ Wv,
                                                const float* __restrict__ Wf,
                                                unsigned short* __restrict__ W2t,
                                                unsigned short* __restrict__ Wft) {
  int bid = blockIdx.x;
  if (bid < 2304) {
    int o = bid * 256 + threadIdx.x;
    int np = o / 768, d = o - np * 768;
    int h = np >> 6, k = np & 63;
    W2t[o] = f2bf(Wv[h * 49152 + d * 64 + k]);
  } else {
    int o = (bid - 2304) * 256 + threadIdx.x;
    int l = o / 589824, rem = o - l * 589824;
    int np = rem / 768, d = rem - np * 768;
    Wft[o] = f2bf(Wf[l * 589824 + d * 768 + np]);
  }
}

// ---------------- row kernels ----------------
__device__ __forceinline__ void wave_reduce2(float& s, float& s2) {
#pragma unroll
  for (int off = 32; off > 0; off >>= 1) {
    s += __shfl_down(s, off);
    s2 += __shfl_down(s2, off);
  }
  s = __shfl(s, 0);
  s2 = __shfl(s2, 0);
}

__global__ __launch_bounds__(256) void ln1_kernel(const float* __restrict__ x,
                                                  const float* __restrict__ sc,
                                                  const float* __restrict__ bi,
                                                  unsigned short* __restrict__ out) {
  int row = blockIdx.x * 4 + (threadIdx.x >> 6);
  int lane = threadIdx.x & 63;
  size_t base = (size_t)row * 768;
  float4 v[3];
#pragma unroll
  for (int j = 0; j < 3; ++j) v[j] = *(const float4*)(x + base + lane * 4 + j * 256);
  float s = 0.f, s2 = 0.f;
#pragma unroll
  for (int j = 0; j < 3; ++j) {
    s += v[j].x + v[j].y + v[j].z + v[j].w;
    s2 += v[j].x * v[j].x + v[j].y * v[j].y + v[j].z * v[j].z + v[j].w * v[j].w;
  }
  wave_reduce2(s, s2);
  float mu = s * (1.0f / 768.0f);
  float var = s2 * (1.0f / 768.0f) - mu * mu;
  float r = rsqrtf(var + 1e-6f);
#pragma unroll
  for (int j = 0; j < 3; ++j) {
    int d = lane * 4 + j * 256;
    float4 scv = *(const float4*)(sc + d);
    float4 biv = *(const float4*)(bi + d);
    us4 o;
    o[0] = f2bf((v[j].x - mu) * r * scv.x + biv.x);
    o[1] = f2bf((v[j].y - mu) * r * scv.y + biv.y);
    o[2] = f2bf((v[j].z - mu) * r * scv.z + biv.z);
    o[3] = f2bf((v[j].w - mu) * r * scv.w + biv.w);
    *(us4*)(out + base + d) = o;
  }
}

__global__ __launch_bounds__(256) void lnswish_kernel(const unsigned short* __restrict__ g,
                                                      const float* __restrict__ sc,
                                                      const float* __restrict__ bi,
                                                      unsigned short* __restrict__ out) {
  int row = blockIdx.x * 4 + (threadIdx.x >> 6);
  int lane = threadIdx.x & 63;
  size_t base = (size_t)row * 768;
  float v[3][4];
#pragma unroll
  for (int j = 0; j < 3; ++j) {
    us4 gv = *(const us4*)(g + base + lane * 4 + j * 256);
#pragma unroll
    for (int q = 0; q < 4; ++q) v[j][q] = bf2f(gv[q]);
  }
  float s = 0.f, s2 = 0.f;
#pragma unroll
  for (int j = 0; j < 3; ++j)
#pragma unroll
    for (int q = 0; q < 4; ++q) { s += v[j][q]; s2 += v[j][q] * v[j][q]; }
  wave_reduce2(s, s2);
  float mu = s * (1.0f / 768.0f);
  float var = s2 * (1.0f / 768.0f) - mu * mu;
  float r = rsqrtf(var + 1e-6f);
#pragma unroll
  for (int j = 0; j < 3; ++j) {
    int d = lane * 4 + j * 256;
    float4 scv = *(const float4*)(sc + d);
    float4 biv = *(const float4*)(bi + d);
    const float* scp = &scv.x;
    const float* bip = &biv.x;
    us4 o;
#pragma unroll
    for (int q = 0; q < 4; ++q) {
      float z = (v[j][q] - mu) * r * scp[q] + bip[q];
      o[q] = f2bf(z / (1.0f + __expf(-z)));
    }
    *(us4*)(out + base + d) = o;
  }
}

// ---------- 256x256 8-phase dense GEMM core (R8 verbatim) ----------
template <int K>
__device__ __forceinline__ void gemm256(const unsigned short* __restrict__ A,
                                        const unsigned short* __restrict__ Bt,
                                        int m0, int n0, unsigned short* lds,
                                        f32x4 acc[8][4]) {
  const int tid = threadIdx.x;
  const int lane = tid & 63;
  const int wid = tid >> 6;
  const int wm = (wid >> 2) << 6;
  const int wn = (wid & 3) << 5;
  const int fm = lane & 15, fq = lane >> 4;
  const int srow = tid >> 3;
  const int sslot = (tid & 7) ^ (srow & 7);
  const size_t abase = (size_t)(m0 + srow) * K + (sslot << 3);
  const size_t bbase = (size_t)(n0 + srow) * K + (sslot << 3);

  bf16x8 aq[4][2], bq[4][2];

#define STG_A(kt, bb, c)                                                     \
  g2l16(A + abase + (size_t)((c) << 6) * K + ((kt) << 6),                    \
        lds + ((bb) << 15) + ((c) << 12) + (tid << 3))
#define STG_B(kt, bb, c)                                                     \
  g2l16(Bt + bbase + (size_t)((c) << 6) * K + ((kt) << 6),                   \
        lds + ((bb) << 15) + 16384 + ((c) << 12) + (tid << 3))
#define LDA(bb, mh)                                                          \
  _Pragma("unroll") for (int mt = 0; mt < 4; ++mt) {                         \
    const unsigned short* p =                                                \
        lds + ((bb) << 15) + (wm + ((mh) << 7) + (mt << 4) + fm) * 64;       \
    _Pragma("unroll") for (int kk = 0; kk < 2; ++kk)                         \
      aq[mt][kk] = *(const bf16x8*)(p + ((((kk << 2) + fq) ^ (fm & 7)) << 3)); \
  }
#define LDB(bb, nh)                                                          \
  _Pragma("unroll") for (int nt = 0; nt < 2; ++nt) {                         \
    const unsigned short* p = lds + ((bb) << 15) + 16384 +                   \
                              (wn + ((nh) << 7) + (nt << 4) + fm) * 64;      \
    _Pragma("unroll") for (int kk = 0; kk < 2; ++kk)                         \
      bq[((nh) << 1) + nt][kk] =                                             \
          *(const bf16x8*)(p + ((((kk << 2) + fq) ^ (fm & 7)) << 3));        \
  }
#define MMX(mh, nh)                                                          \
  {                                                                          \
    __builtin_amdgcn_s_setprio(1);                                           \
    _Pragma("unroll") for (int mt = 0; mt < 4; ++mt)                         \
    _Pragma("unroll") for (int nt = 0; nt < 2; ++nt)                         \
    _Pragma("unroll") for (int kk = 0; kk < 2; ++kk)                         \
      acc[((mh) << 2) + mt][((nh) << 1) + nt] =                              \
          __builtin_amdgcn_mfma_f32_16x16x32_bf16(                           \
              aq[mt][kk], bq[((nh) << 1) + nt][kk],                          \
              acc[((mh) << 2) + mt][((nh) << 1) + nt], 0, 0, 0);             \
    __builtin_amdgcn_s_setprio(0);                                           \
  }

  constexpr int NT = K >> 6;
  STG_A(0, 0, 0); STG_A(0, 0, 1); STG_A(0, 0, 2); STG_A(0, 0, 3);
  STG_B(0, 0, 0); STG_B(0, 0, 1); STG_B(0, 0, 2); STG_B(0, 0, 3);
  STG_A(1, 1, 0); STG_A(1, 1, 1);
  STG_B(1, 1, 0); STG_B(1, 1, 1);
  BARV(4);

  for (int t = 0; t < (NT >> 1) - 1; ++t) {
    const int k1 = 2 * t + 1, k2 = 2 * t + 2, k3 = 2 * t + 3;
    LDA(0, 0); LDB(0, 0);
    STG_A(k1, 1, 2); STG_A(k1, 1, 3);
    MMX(0, 0); BARX;
    LDB(0, 1);
    STG_B(k1, 1, 2); STG_B(k1, 1, 3);
    MMX(0, 1); BARX;
    LDA(0, 1);
    STG_A(k2, 0, 0); STG_A(k2, 0, 1);
    MMX(1, 0); BARX;
    STG_B(k2, 0, 0); STG_B(k2, 0, 1);
    MMX(1, 1); BARV(4);
    LDA(1, 0); LDB(1, 0);
    STG_A(k2, 0, 2); STG_A(k2, 0, 3);
    MMX(0, 0); BARX;
    LDB(1, 1);
    STG_B(k2, 0, 2); STG_B(k2, 0, 3);
    MMX(0, 1); BARX;
    LDA(1, 1);
    STG_A(k3, 1, 0); STG_A(k3, 1, 1);
    MMX(1, 0); BARX;
    STG_B(k3, 1, 0); STG_B(k3, 1, 1);
    MMX(1, 1); BARV(4);
  }
  {
    const int k1 = NT - 1;
    LDA(0, 0); LDB(0, 0);
    STG_A(k1, 1, 2); STG_A(k1, 1, 3);
    MMX(0, 0); BARX;
    LDB(0, 1);
    STG_B(k1, 1, 2); STG_B(k1, 1, 3);
    MMX(0, 1); BARX;
    LDA(0, 1);
    MMX(1, 0); BARX;
    MMX(1, 1);
    BARV(0);
    LDA(1, 0); LDB(1, 0);
    MMX(0, 0); BARX;
    LDB(1, 1);
    MMX(0, 1); BARX;
    LDA(1, 1);
    MMX(1, 0); BARX;
    MMX(1, 1);
  }
#undef STG_A
#undef STG_B
#undef LDA
#undef LDB
#undef MMX
}

__device__ __forceinline__ void decode256(int bid, int& m0, int& n0) {
  int wg = (bid & 7) * 24 + (bid >> 3);
  int mi = wg / 3, ni = wg - mi * 3;
  m0 = mi << 8;
  n0 = ni << 8;
}

// GEMM1: xn @ W2t -> Vt[h][b*64+k][n] (bf16)
__global__ __launch_bounds__(512, 2) void gemm1_256(const unsigned short* __restrict__ A,
                                                    const unsigned short* __restrict__ W2t,
                                                    unsigned short* __restrict__ Vt) {
  extern __shared__ unsigned short lds[];
  f32x4 acc[8][4] = {};
  int m0, n0;
  decode256(blockIdx.x, m0, n0);
  gemm256<768>(A, W2t, m0, n0, lds, acc);
  const int lane = threadIdx.x & 63, wid = threadIdx.x >> 6;
  const int wm = (wid >> 2) << 6, wn = (wid & 3) << 5;
  const int fm = lane & 15, fq = lane >> 4;
#pragma unroll
  for (int ai = 0; ai < 8; ++ai) {
    int rowb = m0 + wm + ((ai >> 2) << 7) + ((ai & 3) << 4) + (fq << 2);
    int b = rowb >> 10, n = rowb & 1023;
#pragma unroll
    for (int nj = 0; nj < 4; ++nj) {
      int col = n0 + wn + ((nj >> 1) << 7) + ((nj & 1) << 4) + fm;
      int h = col >> 6, ck = col & 63;
      size_t off = ((size_t)h << 20) + (size_t)((b << 6) + ck) * 1024 + n;
      us4 v;
#pragma unroll
      for (int r = 0; r < 4; ++r) v[r] = f2bf(acc[ai][nj][r]);
      *(us4*)(Vt + off) = v;
    }
  }
}

// FFN GEMM (layer 0): A(bf16) @ Wt + bias -> g (bf16)
__global__ __launch_bounds__(512, 2) void gemmf_256(const unsigned short* __restrict__ A,
                                                    const unsigned short* __restrict__ Bt,
                                                    const float* __restrict__ bias,
                                                    unsigned short* __restrict__ g) {
  extern __shared__ unsigned short lds[];
  f32x4 acc[8][4] = {};
  int m0, n0;
  decode256(blockIdx.x, m0, n0);
  gemm256<768>(A, Bt, m0, n0, lds, acc);
  const int lane = threadIdx.x & 63, wid = threadIdx.x >> 6;
  const int wm = (wid >> 2) << 6, wn = (wid & 3) << 5;
  const int fm = lane & 15, fq = lane >> 4;
#pragma unroll
  for (int ai = 0; ai < 8; ++ai) {
    int rowb = m0 + wm + ((ai >> 2) << 7) + ((ai & 3) << 4) + (fq << 2);
#pragma unroll
    for (int nj = 0; nj < 4; ++nj) {
      int col = n0 + wn + ((nj >> 1) << 7) + ((nj & 1) << 4) + fm;
      float bc = bias[col];
#pragma unroll
      for (int r = 0; r < 4; ++r)
        g[(size_t)(rowb + r) * 768 + col] = f2bf(acc[ai][nj][r] + bc);
    }
  }
}

// ---------- circ 256x256 8-phase (R8 verbatim) ----------
__global__ __launch_bounds__(512, 2) void circ256_kernel(const float* __restrict__ alpha,
                                                         const unsigned short* __restrict__ Vt,
                                                         const float* __restrict__ xin,
                                                         unsigned short* __restrict__ x2bf) {
  extern __shared__ unsigned short lds[];
  unsigned short* sAc = lds;          // 8*1288 = 10304 shorts
  unsigned short* sB = lds + 10304;   // 2*16384 shorts
  f32x4 acc[8][4] = {};

  int wg = (blockIdx.x & 7) * 24 + (blockIdx.x >> 3);
  int h = wg >> 4, tt = wg & 15;
  int m0 = (tt >> 2) << 8, n0 = (tt & 3) << 8;

  const int tid = threadIdx.x;
  const int lane = tid & 63, wid = tid >> 6;
  const int wm = (wid >> 2) << 6, wn = (wid & 3) << 5;
  const int fm = lane & 15, fq = lane >> 4;
  const int srow = tid >> 3;
  const int sslot = (tid & 7) ^ (srow & 7);

  const float* ah = alpha + (h << 10);
#pragma unroll
  for (int c = 0; c < 8; ++c)
    for (int u = tid; u < 1280; u += 512)
      sAc[c * 1288 + u] = f2bf(ah[(m0 - 769 - u - c) & 1023]);

  const unsigned short* Bt = Vt + ((size_t)h << 20);
  const size_t bbase = (size_t)(n0 + srow) * 1024 + (sslot << 3);

  bf16x8 aq[4][2], bq[4][2];

#define CSTG(kt, bb, c)                                                      \
  g2l16(Bt + bbase + (size_t)((c) << 6) * 1024 + ((kt) << 6),                \
        sB + ((bb) << 14) + ((c) << 12) + (tid << 3))
#define CLDA(kt, mh)                                                         \
  _Pragma("unroll") for (int mt = 0; mt < 4; ++mt)                           \
  _Pragma("unroll") for (int kk = 0; kk < 2; ++kk) {                         \
    int d_ = ((kt) << 6) + (kk << 5) + (fq << 3) + 255 -                     \
             (wm + ((mh) << 7) + (mt << 4) + fm);                            \
    int c_ = d_ & 7;                                                         \
    aq[mt][kk] = *(const bf16x8*)(sAc + c_ * 1288 + (d_ - c_));              \
  }
#define CLDB(bb, nh)                                                         \
  _Pragma("unroll") for (int nt = 0; nt < 2; ++nt) {                         \
    const unsigned short* p =                                                \
        sB + ((bb) << 14) + (wn + ((nh) << 7) + (nt << 4) + fm) * 64;        \
    _Pragma("unroll") for (int kk = 0; kk < 2; ++kk)                         \
      bq[((nh) << 1) + nt][kk] =                                             \
          *(const bf16x8*)(p + ((((kk << 2) + fq) ^ (fm & 7)) << 3));        \
  }
#define CMMX(mh, nh)                                                         \
  {                                                                          \
    __builtin_amdgcn_s_setprio(1);                                           \
    _Pragma("unroll") for (int mt = 0; mt < 4; ++mt)                         \
    _Pragma("unroll") for (int nt = 0; nt < 2; ++nt)                         \
    _Pragma("unroll") for (int kk = 0; kk < 2; ++kk)                         \
      acc[((mh) << 2) + mt][((nh) << 1) + nt] =                              \
          __builtin_amdgcn_mfma_f32_16x16x32_bf16(                           \
              aq[mt][kk], bq[((nh) << 1) + nt][kk],                          \
              acc[((mh) << 2) + mt][((nh) << 1) + nt], 0, 0, 0);             \
    __builtin_amdgcn_s_setprio(0);                                           \
  }

  CSTG(0, 0, 0); CSTG(0, 0, 1); CSTG(0, 0, 2); CSTG(0, 0, 3);
  CSTG(1, 1, 0); CSTG(1, 1, 1);
  BARV(2);

  for (int it = 0; it < 7; ++it) {
    const int k0 = 2 * it, k1 = 2 * it + 1, k2 = 2 * it + 2, k3 = 2 * it + 3;
    CLDA(k0, 0); CLDB(0, 0);
    CSTG(k1, 1, 2);
    CMMX(0, 0); BARX;
    CLDB(0, 1);
    CSTG(k1, 1, 3);
    CMMX(0, 1); BARX;
    CLDA(k0, 1);
    CSTG(k2, 0, 0);
    CMMX(1, 0); BARX;
    CSTG(k2, 0, 1);
    CMMX(1, 1); BARV(2);
    CLDA(k1, 0); CLDB(1, 0);
    CSTG(k2, 0, 2);
    CMMX(0, 0); BARX;
    CLDB(1, 1);
    CSTG(k2, 0, 3);
    CMMX(0, 1); BARX;
    CLDA(k1, 1);
    CSTG(k3, 1, 0);
    CMMX(1, 0); BARX;
    CSTG(k3, 1, 1);
    CMMX(1, 1); BARV(2);
  }
  CLDA(14, 0); CLDB(0, 0);
  CSTG(15, 1, 2);
  CMMX(0, 0); BARX;
  CLDB(0, 1);
  CSTG(15, 1, 3);
  CMMX(0, 1); BARX;
  CLDA(14, 1);
  CMMX(1, 0); BARX;
  CMMX(1, 1);
  BARV(0);
  CLDA(15, 0); CLDB(1, 0);
  CMMX(0, 0); BARX;
  CLDB(1, 1);
  CMMX(0, 1); BARX;
  CLDA(15, 1);
  CMMX(1, 0); BARX;
  CMMX(1, 1);
#undef CSTG
#undef CLDA
#undef CLDB
#undef CMMX

#pragma unroll
  for (int ai = 0; ai < 8; ++ai) {
    int i = m0 + wm + ((ai >> 2) << 7) + ((ai & 3) << 4) + (fq << 2);
#pragma unroll
    for (int nj = 0; nj < 4; ++nj) {
      int col = n0 + wn + ((nj >> 1) << 7) + ((nj & 1) << 4) + fm;
      int b = col >> 6, k = col & 63;
      size_t off = ((size_t)(b << 10) + i) * 768 + (h << 6) + k;
#pragma unroll
      for (int r = 0; r < 4; ++r) {
        float val = acc[ai][nj][r] + xin[off + (size_t)r * 768];
        x2bf[off + (size_t)r * 768] = f2bf(val);
      }
    }
  }
}

// ---------- fused FFN layer-1 GEMM + LN + swish + residual + log_cosh ----
// NON-template, uniform staging (every thread issues exactly 7 g2l16/stage;
// waves 4-7 duplicate the A-tile loads: identical addr, identical data).
// Tile 64 rows x 768 cols (full row -> LN block-local). 8 waves x 96 cols.
// BK=32, 2 LDS buffers. LDS: sA 2x2048 + sB 2x24576 shorts = 104KB.
// grid 256 = one round at 1 block/CU.
__global__ __launch_bounds__(512, 2) void gemmf_ln1(
    const unsigned short* __restrict__ A,
    const unsigned short* __restrict__ Wt,
    const float* __restrict__ bias,
    const float* __restrict__ sc,
    const float* __restrict__ bi,
    const unsigned short* __restrict__ x2,
    float* __restrict__ outp) {
  extern __shared__ unsigned short lds[];
  unsigned short* sA = lds;          // 2 * 2048 shorts (8KB)
  unsigned short* sB = lds + 4096;   // 2 * 24576 shorts (96KB)
  float* fst = (float*)lds;          // stats overlay on sA after drain

  f32x4 acc[4][6] = {};
  int bid = blockIdx.x;
  int p = ((bid & 7) << 5) + (bid >> 3);   // bijective XCD swizzle (256%8==0)
  const int m0 = p << 6;

  const int tid = threadIdx.x;
  const int lane = tid & 63;
  const int wid = tid >> 6;
  const int fm = lane & 15, fq = lane >> 4;
  const int wc0 = wid * 96;
  const int brow = tid >> 2;              // 0..127 (B staging row-within-chunk)
  const int cg = tid & 3;
  // B: slot swizzle ((r>>1)&3) is c-independent since c*128>>1 ≡ 0 mod 4
  const size_t wbase = (size_t)brow * 768 + ((cg ^ ((brow >> 1) & 3)) << 3);
  // A: waves 4-7 duplicate waves 0-3 (t2 = tid&255)
  const int t2 = tid & 255;
  const int ar = t2 >> 2;                 // 0..63
  const size_t abase = (size_t)(m0 + ar) * 768 + ((cg ^ ((ar >> 1) & 3)) << 3);

#define FSTG(step, buf)                                                      \
  {                                                                          \
    int k0_ = (step) << 5;                                                   \
    _Pragma("unroll") for (int c = 0; c < 6; ++c)                            \
      g2l16(Wt + wbase + c * 98304 + k0_,                                    \
            sB + (buf) * 24576 + c * 4096 + (tid << 3));                     \
    g2l16(A + abase + k0_, sA + (buf) * 2048 + (t2 << 3));                   \
  }
#define FCOMP(buf)                                                           \
  {                                                                          \
    bf16x8 aq[4], bq[6];                                                     \
    _Pragma("unroll") for (int mt = 0; mt < 4; ++mt) {                       \
      int ra = (mt << 4) + fm;                                               \
      aq[mt] = *(const bf16x8*)(sA + (buf) * 2048 + (ra << 5) +              \
                                ((fq ^ ((ra >> 1) & 3)) << 3));              \
    }                                                                        \
    _Pragma("unroll") for (int nt = 0; nt < 6; ++nt) {                       \
      int rb = wc0 + (nt << 4) + fm;                                         \
      bq[nt] = *(const bf16x8*)(sB + (buf) * 24576 + (rb << 5) +             \
                                ((fq ^ ((rb >> 1) & 3)) << 3));              \
    }                                                                        \
    __builtin_amdgcn_s_setprio(1);                                           \
    _Pragma("unroll") for (int mt = 0; mt < 4; ++mt)                         \
    _Pragma("unroll") for (int nt = 0; nt < 6; ++nt)                         \
      acc[mt][nt] = __builtin_amdgcn_mfma_f32_16x16x32_bf16(                 \
          aq[mt], bq[nt], acc[mt][nt], 0, 0, 0);                             \
    __builtin_amdgcn_s_setprio(0);                                           \
  }

  FSTG(0, 0);
  for (int it = 0; it < 24; ++it) {
    WAITB(0);                       // stage(it) landed; prev reads retired
    if (it < 23) FSTG(it + 1, (it + 1) & 1);
    FCOMP(it & 1);
  }
  __syncthreads();  // full drain before stats overlay on sA region

  float bc[6];
#pragma unroll
  for (int nt = 0; nt < 6; ++nt) bc[nt] = bias[wc0 + (nt << 4) + fm];
#pragma unroll
  for (int mt = 0; mt < 4; ++mt)
#pragma unroll
    for (int nt = 0; nt < 6; ++nt)
#pragma unroll
      for (int r = 0; r < 4; ++r) acc[mt][nt][r] += bc[nt];

  float s[4][4], s2[4][4];
#pragma unroll
  for (int mt = 0; mt < 4; ++mt)
#pragma unroll
    for (int r = 0; r < 4; ++r) {
      float a = 0.f, b2 = 0.f;
#pragma unroll
      for (int nt = 0; nt < 6; ++nt) {
        float v = acc[mt][nt][r];
        a += v;
        b2 += v * v;
      }
      s[mt][r] = a;
      s2[mt][r] = b2;
    }
#pragma unroll
  for (int off = 1; off <= 8; off <<= 1)
#pragma unroll
    for (int mt = 0; mt < 4; ++mt)
#pragma unroll
      for (int r = 0; r < 4; ++r) {
        s[mt][r] += __shfl_xor(s[mt][r], off);
        s2[mt][r] += __shfl_xor(s2[mt][r], off);
      }
  if (fm == 0) {
#pragma unroll
    for (int mt = 0; mt < 4; ++mt)
#pragma unroll
      for (int r = 0; r < 4; ++r) {
        int row = (mt << 4) + (fq << 2) + r;
        fst[wid * 64 + row] = s[mt][r];
        fst[512 + wid * 64 + row] = s2[mt][r];
      }
  }
  __syncthreads();
  if (tid < 64) {
    float ts = 0.f, ts2 = 0.f;
#pragma unroll
    for (int w = 0; w < 8; ++w) {
      ts += fst[w * 64 + tid];
      ts2 += fst[512 + w * 64 + tid];
    }
    float mu = ts * (1.0f / 768.0f);
    float var = ts2 * (1.0f / 768.0f) - mu * mu;
    fst[1024 + tid] = mu;
    fst[1088 + tid] = rsqrtf(var + 1e-6f);
  }
  __syncthreads();

  float scv[6], biv[6];
#pragma unroll
  for (int nt = 0; nt < 6; ++nt) {
    scv[nt] = sc[wc0 + (nt << 4) + fm];
    biv[nt] = bi[wc0 + (nt << 4) + fm];
  }
#pragma unroll
  for (int mt = 0; mt < 4; ++mt)
#pragma unroll
    for (int r = 0; r < 4; ++r) {
      int row = (mt << 4) + (fq << 2) + r;
      float mu = fst[1024 + row];
      float rr = fst[1088 + row];
      size_t rg = (size_t)(m0 + row) * 768;
#pragma unroll
      for (int nt = 0; nt < 6; ++nt) {
        int col = wc0 + (nt << 4) + fm;
        float z = (acc[mt][nt][r] - mu) * rr * scv[nt] + biv[nt];
        float sw = z / (1.0f + __expf(-z));
        float t = sw + bf2f(x2[rg + col]);
        float ax = fabsf(t);
        outp[rg + col] =
            ax + __logf(1.0f + __expf(-2.0f * ax)) - 0.69314718055994531f;
      }
    }
#undef FSTG
#undef FCOMP
}

extern "C" void kernel_launch(void* const* d_in, const int* in_sizes, int n_in,
                              void* d_out, int out_size, void* d_ws, size_t ws_size,
                              hipStream_t stream) {
  const float* x = (const float*)d_in[0];
  const float* ln1_s = (const float*)d_in[1];
  const float* ln1_b = (const float*)d_in[2];
  const float* Wv = (const float*)d_in[3];
  const float* alpha = (const float*)d_in[4];
  const float* Wf = (const float*)d_in[5];
  const float* bf = (const float*)d_in[6];
  const float* lnf_s = (const float*)d_in[7];
  const float* lnf_b = (const float*)d_in[8];
  float* out = (float*)d_out;

  char* ws = (char*)d_ws;
  unsigned short* slotA = (unsigned short*)ws;
  unsigned short* Vt = (unsigned short*)(ws + 25165824);
  unsigned short* gbf = Vt;
  unsigned short* slotX = (unsigned short*)(ws + 50331648);
  unsigned short* W2t = (unsigned short*)(ws + 75497472);
  unsigned short* Wft = (unsigned short*)(ws + 76677120);

  hipFuncSetAttribute((const void*)gemm1_256,
                      hipFuncAttributeMaxDynamicSharedMemorySize, 131072);
  hipFuncSetAttribute((const void*)gemmf_256,
                      hipFuncAttributeMaxDynamicSharedMemorySize, 131072);
  hipFuncSetAttribute((const void*)circ256_kernel,
                      hipFuncAttributeMaxDynamicSharedMemorySize, 86144);
  hipFuncSetAttribute((const void*)gemmf_ln1,
                      hipFuncAttributeMaxDynamicSharedMemorySize, 106496);

  pack_all<<<6912, 256, 0, stream>>>(Wv, Wf, W2t, Wft);

  ln1_kernel<<<4096, 256, 0, stream>>>(x, ln1_s, ln1_b, slotA);
  gemm1_256<<<192, 512, 131072, stream>>>(slotA, W2t, Vt);
  circ256_kernel<<<192, 512, 86144, stream>>>(alpha, Vt, x, slotX);
  // FFN layer 0 (R8 path): gemm + bias -> gbf ; lnswish -> slotA
  gemmf_256<<<192, 512, 131072, stream>>>(slotX, Wft, bf, gbf);
  lnswish_kernel<<<4096, 256, 0, stream>>>(gbf, lnf_s, lnf_b, slotA);
  // FFN layer 1 fused: gemm + bias + LN + swish + residual + log_cosh -> out
  gemmf_ln1<<<256, 512, 106496, stream>>>(slotA, Wft + 589824, bf + 768,
                                          lnf_s + 768, lnf_b + 768, slotX,
                                          out);
}